// Round 1
// baseline (1117.585 us; speedup 1.0000x reference)
//
#include <hip/hip_runtime.h>
#include <stdint.h>

// ---------------------------------------------------------------------------
// EnhancedXLSTM on MI355X (gfx950).
// Round 1: correct bf16-MFMA implementation.
//   - All big GEMMs via one segmented-K bf16 MFMA kernel (m97 structure:
//     128x128 tile, BK=64, global_load_lds width 16, 16x16x32 bf16 MFMA).
//   - Weights/activations converted fp32->bf16 once per call; accumulation,
//     LN stats, transcendentals all fp32.
//   - Scratch budget ~270 MB with buffer aliasing (gates per-s reuse).
// ---------------------------------------------------------------------------

#define Bq 16384
#define Dq 512
#define Sq 3
#define Hq 8

typedef unsigned short u16;
typedef __bf16 bf16x8 __attribute__((ext_vector_type(8)));
typedef float f32x4 __attribute__((ext_vector_type(4)));
typedef u16 u16x8 __attribute__((ext_vector_type(8)));
typedef u16 u16x4v __attribute__((ext_vector_type(4)));

__device__ __forceinline__ u16 f2bf(float f) {
    union { float f; uint32_t u; } c; c.f = f;
    uint32_t u = c.u;
    return (u16)((u + 0x7fffu + ((u >> 16) & 1u)) >> 16);   // RNE
}
__device__ __forceinline__ float bf2f(u16 h) {
    union { uint32_t u; float f; } c; c.u = ((uint32_t)h) << 16;
    return c.f;
}

__device__ __forceinline__ void async16(const u16* g, u16* l) {
    __builtin_amdgcn_global_load_lds(
        (__attribute__((address_space(1))) void*)const_cast<u16*>(g),
        (__attribute__((address_space(3))) void*)l, 16, 0, 0);
}

// ---------------------------------------------------------------------------
// fp32 -> bf16 convert (vectorized, memory-bound)
// ---------------------------------------------------------------------------
__global__ __launch_bounds__(256) void cvt_kernel(const float* __restrict__ in,
                                                  u16* __restrict__ out, long long n)
{
    long long i = ((long long)blockIdx.x * 256 + threadIdx.x) * 4;
    if (i >= n) return;
    float4 v = *(const float4*)(in + i);
    u16x4v o; o[0] = f2bf(v.x); o[1] = f2bf(v.y); o[2] = f2bf(v.z); o[3] = f2bf(v.w);
    *(u16x4v*)(out + i) = o;
}

// ---------------------------------------------------------------------------
// Segmented-K bf16 GEMM:  C[z] = sum_seg A_seg[z] @ W_seg[z]^T + bias0(+bias1)
// A: (M,K) row-major bf16.  W: (N,K) row-major bf16 (k-contiguous).
// Each segment has K=512.  Tile 128x128, BK=64, 256 threads (2x2 waves,
// each wave a 4x4 grid of 16x16x32 MFMAs).
// ---------------------------------------------------------------------------
struct Seg {
    const u16* A; long long Az; int lda;
    const u16* W; long long Wz; int ldw;
};

template<int NSEG, int OUTBF>
__global__ __launch_bounds__(256, 2)
void gemm_seg_kernel(Seg s0, Seg s1, Seg s2, Seg s3,
                     const float* __restrict__ bias0, long long b0z,
                     const float* __restrict__ bias1,
                     void* __restrict__ outp, long long outz, int ldo)
{
    __shared__ u16 As[128 * 64];   // 16 KB
    __shared__ u16 Bs[128 * 64];   // 16 KB
    const int tid  = threadIdx.x;
    const int lane = tid & 63;
    const int wv   = tid >> 6;
    const int wm   = wv >> 1, wn = wv & 1;
    const int z    = blockIdx.z;
    const long long rowBase = (long long)blockIdx.y * 128;
    const long long colBase = (long long)blockIdx.x * 128;

    f32x4 acc[4][4];
#pragma unroll
    for (int a = 0; a < 4; ++a)
#pragma unroll
        for (int b = 0; b < 4; ++b) acc[a][b] = (f32x4){0.f, 0.f, 0.f, 0.f};

    const int srow  = tid >> 3;        // 0..31  staging row within 32-row group
    const int scol  = (tid & 7) << 3;  // 0..56  staging col (8 bf16 = 16B)
    const int lrow  = lane & 15;
    const int lquad = lane >> 4;

    const Seg segs[4] = {s0, s1, s2, s3};

#pragma unroll
    for (int sg = 0; sg < NSEG; ++sg) {
        const int lda = segs[sg].lda, ldw = segs[sg].ldw;
        const u16* Ab = segs[sg].A + (long long)z * segs[sg].Az
                        + (rowBase + srow) * (long long)lda + scol;
        const u16* Wb = segs[sg].W + (long long)z * segs[sg].Wz
                        + (colBase + srow) * (long long)ldw + scol;
        for (int kt = 0; kt < 512; kt += 64) {
#pragma unroll
            for (int i = 0; i < 4; ++i) {
                async16(Ab + (long long)(i * 32) * lda + kt, &As[(i * 32 + srow) * 64 + scol]);
                async16(Wb + (long long)(i * 32) * ldw + kt, &Bs[(i * 32 + srow) * 64 + scol]);
            }
            __syncthreads();   // compiler inserts vmcnt(0) drain for the LDS DMAs
#pragma unroll
            for (int kk = 0; kk < 64; kk += 32) {
                bf16x8 af[4], bw[4];
#pragma unroll
                for (int t = 0; t < 4; ++t)
                    af[t] = *(const bf16x8*)&As[(wm * 64 + t * 16 + lrow) * 64 + kk + lquad * 8];
#pragma unroll
                for (int t = 0; t < 4; ++t)
                    bw[t] = *(const bf16x8*)&Bs[(wn * 64 + t * 16 + lrow) * 64 + kk + lquad * 8];
#pragma unroll
                for (int mt = 0; mt < 4; ++mt)
#pragma unroll
                    for (int nt = 0; nt < 4; ++nt)
                        acc[mt][nt] = __builtin_amdgcn_mfma_f32_16x16x32_bf16(
                            af[mt], bw[nt], acc[mt][nt], 0, 0, 0);
            }
            __syncthreads();
        }
    }

    // epilogue: C/D layout col=lane&15, row=(lane>>4)*4+reg  [m89-verified]
#pragma unroll
    for (int nt = 0; nt < 4; ++nt) {
        const long long col = colBase + wn * 64 + nt * 16 + lrow;
        float bvv = bias0[z * b0z + col];
        if (bias1) bvv += bias1[col];
#pragma unroll
        for (int mt = 0; mt < 4; ++mt) {
            const long long row0 = rowBase + wm * 64 + mt * 16 + lquad * 4;
#pragma unroll
            for (int r = 0; r < 4; ++r) {
                const float val = acc[mt][nt][r] + bvv;
                const long long o = z * outz + (row0 + r) * (long long)ldo + col;
                if (OUTBF) ((u16*)outp)[o] = f2bf(val);
                else       ((float*)outp)[o] = val;
            }
        }
    }
}

// ---------------------------------------------------------------------------
// LayerNorm + exact GELU, in-place on bf16 xs (S,B,D). One wave per row.
// ---------------------------------------------------------------------------
__global__ __launch_bounds__(256) void ln_gelu_kernel(u16* __restrict__ xs,
                                                      const float* __restrict__ ln_g,
                                                      const float* __restrict__ ln_b)
{
    const int lane = threadIdx.x & 63;
    const int wvi  = threadIdx.x >> 6;
    const long long row = (long long)blockIdx.x * 4 + wvi;   // row in [0, S*B)
    const int s = (int)(row / Bq);
    u16* p = xs + row * Dq + lane * 8;
    u16x8 u = *(const u16x8*)p;
    float v[8];
    float sum = 0.f, sq = 0.f;
#pragma unroll
    for (int j = 0; j < 8; ++j) { v[j] = bf2f(u[j]); sum += v[j]; sq += v[j] * v[j]; }
#pragma unroll
    for (int m = 32; m >= 1; m >>= 1) { sum += __shfl_xor(sum, m, 64); sq += __shfl_xor(sq, m, 64); }
    const float mu   = sum * (1.f / 512.f);
    const float var  = sq * (1.f / 512.f) - mu * mu;
    const float rstd = rsqrtf(var + 1e-5f);
    const float* g = ln_g + (size_t)s * Dq + lane * 8;
    const float* b = ln_b + (size_t)s * Dq + lane * 8;
    u16x8 o;
#pragma unroll
    for (int j = 0; j < 8; ++j) {
        float y  = (v[j] - mu) * rstd * g[j] + b[j];
        float ge = 0.5f * y * (1.f + erff(y * 0.70710678118654752f));   // exact GELU
        o[j] = f2bf(ge);
    }
    *(u16x8*)p = o;
}

// ---------------------------------------------------------------------------
// LSTM pointwise for one s: gates(bf16, B x 4D) + c_prev -> h_new/c_new (fp32
// into d_out) + h_new bf16 copy for downstream GEMMs.
// ---------------------------------------------------------------------------
__global__ __launch_bounds__(256) void lstm_kernel(const u16* __restrict__ gates,
                                                   const float* __restrict__ cprev,
                                                   const float* __restrict__ decays, int s,
                                                   float* __restrict__ hout,
                                                   float* __restrict__ cout,
                                                   u16* __restrict__ hbf)
{
    const long long i = ((long long)blockIdx.x * 256 + threadIdx.x) * 4;
    const long long bi = i >> 9;
    const int d = (int)(i & 511);
    const u16* g = gates + bi * 2048 + d;
    u16x4v ig = *(const u16x4v*)(g);
    u16x4v fg = *(const u16x4v*)(g + 512);
    u16x4v gg = *(const u16x4v*)(g + 1024);
    u16x4v og = *(const u16x4v*)(g + 1536);
    float4 cp4 = *(const float4*)(cprev + i);
    float cpa[4] = {cp4.x, cp4.y, cp4.z, cp4.w};
    const float dec = decays[s];
    float hv[4], cv[4]; u16x4v hb;
#pragma unroll
    for (int j = 0; j < 4; ++j) {
        float igf = 1.f / (1.f + expf(-bf2f(ig[j])));
        float fgf = 1.f / (1.f + expf(-bf2f(fg[j])));
        float ggf = tanhf(bf2f(gg[j]));
        float ogf = 1.f / (1.f + expf(-bf2f(og[j])));
        float cl  = fgf * cpa[j] + igf * ggf;
        float hn  = ogf * tanhf(cl);
        hv[j] = hn;
        cv[j] = dec * cpa[j] + (1.f - dec) * cl;
        hb[j] = f2bf(hn);
    }
    *(float4*)(hout + i) = make_float4(hv[0], hv[1], hv[2], hv[3]);
    *(float4*)(cout + i) = make_float4(cv[0], cv[1], cv[2], cv[3]);
    *(u16x4v*)(hbf + i)  = hb;
}

// ---------------------------------------------------------------------------
// Attention over S=3. One wave per (b,h); lane = head-dim element.
// ---------------------------------------------------------------------------
__global__ __launch_bounds__(256) void attn_kernel(const u16* __restrict__ q,
                                                   const u16* __restrict__ k,
                                                   const u16* __restrict__ v,
                                                   u16* __restrict__ fused)
{
    const int lane = threadIdx.x & 63;
    const int wvi  = threadIdx.x >> 6;
    const long long idx = (long long)blockIdx.x * 4 + wvi;   // b*H + h
    const long long off = idx * 64 + lane;                   // = b*512 + h*64 + lane
    const float qv = bf2f(q[off]);
    float sc[3];
#pragma unroll
    for (int s = 0; s < 3; ++s) {
        float p = qv * bf2f(k[(long long)s * Bq * Dq + off]);
#pragma unroll
        for (int m = 32; m >= 1; m >>= 1) p += __shfl_xor(p, m, 64);
        sc[s] = p * 0.125f;   // 1/sqrt(64)
    }
    const float mx = fmaxf(sc[0], fmaxf(sc[1], sc[2]));
    const float e0 = expf(sc[0] - mx), e1 = expf(sc[1] - mx), e2 = expf(sc[2] - mx);
    const float inv = 1.f / (e0 + e1 + e2);
    const float f = (e0 * bf2f(v[off]) +
                     e1 * bf2f(v[(long long)Bq * Dq + off]) +
                     e2 * bf2f(v[2LL * Bq * Dq + off])) * inv;
    fused[off] = f2bf(f);
}

// ---------------------------------------------------------------------------
// Host launcher
// ---------------------------------------------------------------------------
extern "C" void kernel_launch(void* const* d_in, const int* in_sizes, int n_in,
                              void* d_out, int out_size, void* d_ws, size_t ws_size,
                              hipStream_t stream)
{
    (void)in_sizes; (void)n_in; (void)out_size; (void)ws_size;

    const float* x         = (const float*)d_in[0];
    const float* h_prev    = (const float*)d_in[1];
    const float* c_prev    = (const float*)d_in[2];
    const float* ssm       = (const float*)d_in[3];
    const float* Wt        = (const float*)d_in[4];
    const float* bt        = (const float*)d_in[5];
    const float* ln_g      = (const float*)d_in[6];
    const float* ln_b      = (const float*)d_in[7];
    const float* W_ih      = (const float*)d_in[8];
    const float* W_hh      = (const float*)d_in[9];
    const float* b_ih      = (const float*)d_in[10];
    const float* b_hh      = (const float*)d_in[11];
    const float* decays    = (const float*)d_in[12];
    const float* in_proj_w = (const float*)d_in[13];
    const float* in_proj_b = (const float*)d_in[14];
    const float* out_proj_w= (const float*)d_in[15];
    const float* out_proj_b= (const float*)d_in[16];
    const float* mix_w     = (const float*)d_in[17];
    const float* mix_b     = (const float*)d_in[18];
    float* out = (float*)d_out;

    // ---- workspace layout (bf16 elements), ~270 MB peak with aliasing ----
    u16* base = (u16*)d_ws;
    size_t off = 0;
    auto walloc = [&](size_t n) { u16* p = base + off; off += (n + 4095) & ~(size_t)4095; return p; };
    u16* wt_bf    = walloc((size_t)Sq * Dq * Dq);
    u16* wih_bf   = walloc((size_t)Sq * 4 * Dq * Dq);
    u16* whh_bf   = walloc((size_t)Sq * 4 * Dq * Dq);
    u16* inpj_bf  = walloc((size_t)3 * Dq * Dq);
    u16* outpj_bf = walloc((size_t)Dq * Dq);
    u16* mix_bf   = walloc((size_t)Dq * Sq * Dq);
    u16* x_bf     = walloc((size_t)Bq * Dq);
    u16* ssm_bf   = walloc((size_t)Bq * Dq);
    u16* hprev_bf = walloc((size_t)Sq * Bq * Dq);
    u16* xs_bf    = walloc((size_t)Sq * Bq * Dq);
    u16* gates_bf = walloc((size_t)Bq * 4 * Dq);
    u16* hnew_bf  = walloc((size_t)Sq * Bq * Dq);
    u16* k_bf = xs_bf;                          // xs dead after gates GEMMs
    u16* v_bf = hprev_bf;                       // h_prev dead after gates GEMMs
    u16* q_bf = gates_bf;                       // gates dead after LSTM loop
    u16* fu_bf = gates_bf + (size_t)Bq * Dq;

    auto cvt = [&](const float* s, u16* dst, long long n) {
        cvt_kernel<<<dim3((unsigned)((n / 4 + 255) / 256)), 256, 0, stream>>>(s, dst, n);
    };
    cvt(x,          x_bf,     (long long)Bq * Dq);
    cvt(ssm,        ssm_bf,   (long long)Bq * Dq);
    cvt(h_prev,     hprev_bf, (long long)Sq * Bq * Dq);
    cvt(Wt,         wt_bf,    (long long)Sq * Dq * Dq);
    cvt(W_ih,       wih_bf,   (long long)Sq * 4 * Dq * Dq);
    cvt(W_hh,       whh_bf,   (long long)Sq * 4 * Dq * Dq);
    cvt(in_proj_w,  inpj_bf,  (long long)3 * Dq * Dq);
    cvt(out_proj_w, outpj_bf, (long long)Dq * Dq);
    cvt(mix_w,      mix_bf,   (long long)Dq * Sq * Dq);

    Seg zs{nullptr, 0, 0, nullptr, 0, 0};

    // xs[s] = x @ Wt[s]^T + bt[s]     (z-batched over S)
    {
        Seg a{x_bf, 0, Dq, wt_bf, (long long)Dq * Dq, Dq};
        gemm_seg_kernel<1, 1><<<dim3(Dq / 128, Bq / 128, Sq), 256, 0, stream>>>(
            a, zs, zs, zs, bt, Dq, nullptr, xs_bf, (long long)Bq * Dq, Dq);
    }
    ln_gelu_kernel<<<dim3(Sq * Bq / 4), 256, 0, stream>>>(xs_bf, ln_g, ln_b);

    // gates + LSTM pointwise, per s (reuses one gates buffer)
    for (int s = 0; s < Sq; ++s) {
        Seg a{xs_bf + (size_t)s * Bq * Dq, 0, Dq, wih_bf + (size_t)s * 4 * Dq * Dq, 0, Dq};
        Seg b{hprev_bf + (size_t)s * Bq * Dq, 0, Dq, whh_bf + (size_t)s * 4 * Dq * Dq, 0, Dq};
        gemm_seg_kernel<2, 1><<<dim3(4 * Dq / 128, Bq / 128, 1), 256, 0, stream>>>(
            a, b, zs, zs, b_ih + (size_t)s * 4 * Dq, 0, b_hh + (size_t)s * 4 * Dq,
            gates_bf, 0, 4 * Dq);
        lstm_kernel<<<dim3(Bq * Dq / 1024), 256, 0, stream>>>(
            gates_bf, c_prev + (size_t)s * Bq * Dq, decays, s,
            out + (size_t)Bq * Dq + (size_t)s * Bq * Dq,          // h_new slot
            out + (size_t)4 * Bq * Dq + (size_t)s * Bq * Dq,      // c_new slot
            hnew_bf + (size_t)s * Bq * Dq);
    }

    // q = ssm_state @ Wq^T + bq
    {
        Seg a{ssm_bf, 0, Dq, inpj_bf, 0, Dq};
        gemm_seg_kernel<1, 1><<<dim3(Dq / 128, Bq / 128, 1), 256, 0, stream>>>(
            a, zs, zs, zs, in_proj_b, 0, nullptr, q_bf, 0, Dq);
    }
    // k[s] = h_new[s] @ Wk^T + bk   (z over S)
    {
        Seg a{hnew_bf, (long long)Bq * Dq, Dq, inpj_bf + (size_t)Dq * Dq, 0, Dq};
        gemm_seg_kernel<1, 1><<<dim3(Dq / 128, Bq / 128, Sq), 256, 0, stream>>>(
            a, zs, zs, zs, in_proj_b + Dq, 0, nullptr, k_bf, (long long)Bq * Dq, Dq);
    }
    // v[s] = h_new[s] @ Wv^T + bv
    {
        Seg a{hnew_bf, (long long)Bq * Dq, Dq, inpj_bf + (size_t)2 * Dq * Dq, 0, Dq};
        gemm_seg_kernel<1, 1><<<dim3(Dq / 128, Bq / 128, Sq), 256, 0, stream>>>(
            a, zs, zs, zs, in_proj_b + 2 * Dq, 0, nullptr, v_bf, (long long)Bq * Dq, Dq);
    }

    attn_kernel<<<dim3(Bq * Hq / 4), 256, 0, stream>>>(q_bf, k_bf, v_bf, fu_bf);

    // out = sum_s h_new[s] @ mix_w[:, s*D:(s+1)*D]^T + fused @ out_proj^T
    //       + mix_b + out_proj_b          (4 K-segments; multi-transpose folded)
    {
        Seg a0{hnew_bf, 0, Dq, mix_bf, 0, Sq * Dq};
        Seg a1{hnew_bf + (size_t)Bq * Dq, 0, Dq, mix_bf + Dq, 0, Sq * Dq};
        Seg a2{hnew_bf + (size_t)2 * Bq * Dq, 0, Dq, mix_bf + 2 * Dq, 0, Sq * Dq};
        Seg a3{fu_bf, 0, Dq, outpj_bf, 0, Dq};
        gemm_seg_kernel<4, 0><<<dim3(Dq / 128, Bq / 128, 1), 256, 0, stream>>>(
            a0, a1, a2, a3, mix_b, 0, out_proj_b, out, 0, Dq);
    }
}

// Round 2
// 1016.836 us; speedup vs baseline: 1.0991x; 1.0991x over previous
//
#include <hip/hip_runtime.h>
#include <stdint.h>

// ---------------------------------------------------------------------------
// EnhancedXLSTM on MI355X (gfx950).  Round 2:
//   - LDS bank-conflict swizzle in the GEMM (global-source chunk XOR, since
//     global_load_lds dest is wave-linear) -> ds_read_b128 spreads 32 banks.
//   - Launch fusion: 19 -> 8 dispatches (1 cvt, gates z=3, lstm z=3, qkv z=7).
// ---------------------------------------------------------------------------

#define Bq 16384
#define Dq 512
#define Sq 3
#define Hq 8

typedef unsigned short u16;
typedef __bf16 bf16x8 __attribute__((ext_vector_type(8)));
typedef float f32x4 __attribute__((ext_vector_type(4)));
typedef u16 u16x8 __attribute__((ext_vector_type(8)));
typedef u16 u16x4v __attribute__((ext_vector_type(4)));

__device__ __forceinline__ u16 f2bf(float f) {
    union { float f; uint32_t u; } c; c.f = f;
    uint32_t u = c.u;
    return (u16)((u + 0x7fffu + ((u >> 16) & 1u)) >> 16);   // RNE
}
__device__ __forceinline__ float bf2f(u16 h) {
    union { uint32_t u; float f; } c; c.u = ((uint32_t)h) << 16;
    return c.f;
}

__device__ __forceinline__ void async16(const u16* g, u16* l) {
    __builtin_amdgcn_global_load_lds(
        (__attribute__((address_space(1))) void*)const_cast<u16*>(g),
        (__attribute__((address_space(3))) void*)l, 16, 0, 0);
}

// ---------------------------------------------------------------------------
// Fused fp32 -> bf16 convert over up to 9 tensors in one launch.
// ---------------------------------------------------------------------------
struct CvtArgs {
    const float* src[9];
    u16* dst[9];
    long long bound[9];   // inclusive-scan element bounds (bound[8] == total)
};

__global__ __launch_bounds__(256) void cvt_all_kernel(CvtArgs a, long long total)
{
    long long i = ((long long)blockIdx.x * 256 + threadIdx.x) * 4;
    if (i >= total) return;
    const float* s = a.src[0];
    u16* d = a.dst[0];
    long long base = 0;
#pragma unroll
    for (int t = 0; t < 8; ++t) {
        if (i >= a.bound[t]) { s = a.src[t + 1]; d = a.dst[t + 1]; base = a.bound[t]; }
    }
    const long long l = i - base;
    float4 v = *(const float4*)(s + l);
    u16x4v o; o[0] = f2bf(v.x); o[1] = f2bf(v.y); o[2] = f2bf(v.z); o[3] = f2bf(v.w);
    *(u16x4v*)(d + l) = o;
}

// ---------------------------------------------------------------------------
// Segmented-K bf16 GEMM core.  A: (M,K) rm bf16.  W: (N,K) rm bf16.
// K = 512 per segment.  Tile 128x128, BK=64, 256 threads, 2x2 waves of
// 4x4 16x16x32 MFMAs.  XOR-swizzled LDS (swizzle applied on the GLOBAL
// source chunk because global_load_lds dest addr is wave-linear).
// ---------------------------------------------------------------------------
struct SegR { const u16* A; int lda; const u16* W; int ldw; };
struct Seg  { const u16* A; long long Az; int lda; const u16* W; long long Wz; int ldw; };

template<int NSEG, int OUTBF>
__device__ __forceinline__ void gemm_core(const SegR* segs,
                                          const float* __restrict__ bias0,
                                          const float* __restrict__ bias1,
                                          void* __restrict__ outp, int ldo)
{
    __shared__ u16 As[128 * 64];   // 16 KB
    __shared__ u16 Bs[128 * 64];   // 16 KB
    const int tid  = threadIdx.x;
    const int lane = tid & 63;
    const int wv   = tid >> 6;
    const int wm   = wv >> 1, wn = wv & 1;
    const long long rowBase = (long long)blockIdx.y * 128;
    const long long colBase = (long long)blockIdx.x * 128;

    f32x4 acc[4][4];
#pragma unroll
    for (int a = 0; a < 4; ++a)
#pragma unroll
        for (int b = 0; b < 4; ++b) acc[a][b] = (f32x4){0.f, 0.f, 0.f, 0.f};

    const int srow  = tid >> 3;                              // 0..31
    const int swcol = (((tid & 7) ^ (srow & 7)) << 3);       // swizzled SRC col (elems)
    const int dcol  = (tid & 7) << 3;                        // linear LDS dest col
    const int lrow  = lane & 15;
    const int lquad = lane >> 4;

#pragma unroll
    for (int sg = 0; sg < NSEG; ++sg) {
        const int lda = segs[sg].lda, ldw = segs[sg].ldw;
        const u16* Ab = segs[sg].A + (rowBase + srow) * (long long)lda + swcol;
        const u16* Wb = segs[sg].W + (colBase + srow) * (long long)ldw + swcol;
        for (int kt = 0; kt < 512; kt += 64) {
#pragma unroll
            for (int i = 0; i < 4; ++i) {
                async16(Ab + (long long)(i * 32) * lda + kt, &As[(i * 32 + srow) * 64 + dcol]);
                async16(Wb + (long long)(i * 32) * ldw + kt, &Bs[(i * 32 + srow) * 64 + dcol]);
            }
            __syncthreads();   // vmcnt(0) drain for the LDS DMAs inserted here
#pragma unroll
            for (int kk = 0; kk < 64; kk += 32) {
                // un-swizzle: LDS chunk = wantedChunk ^ (row & 7); row&7 == lrow&7
                const int ca = ((((kk >> 3) + lquad) ^ (lrow & 7)) << 3);
                bf16x8 af[4], bw[4];
#pragma unroll
                for (int t = 0; t < 4; ++t)
                    af[t] = *(const bf16x8*)&As[(wm * 64 + t * 16 + lrow) * 64 + ca];
#pragma unroll
                for (int t = 0; t < 4; ++t)
                    bw[t] = *(const bf16x8*)&Bs[(wn * 64 + t * 16 + lrow) * 64 + ca];
#pragma unroll
                for (int mt = 0; mt < 4; ++mt)
#pragma unroll
                    for (int nt = 0; nt < 4; ++nt)
                        acc[mt][nt] = __builtin_amdgcn_mfma_f32_16x16x32_bf16(
                            af[mt], bw[nt], acc[mt][nt], 0, 0, 0);
            }
            __syncthreads();
        }
    }

    // epilogue: C/D layout col=lane&15, row=(lane>>4)*4+reg  [m89-verified]
#pragma unroll
    for (int nt = 0; nt < 4; ++nt) {
        const long long col = colBase + wn * 64 + nt * 16 + lrow;
        float bvv = bias0[col];
        if (bias1) bvv += bias1[col];
#pragma unroll
        for (int mt = 0; mt < 4; ++mt) {
            const long long row0 = rowBase + wm * 64 + mt * 16 + lquad * 4;
#pragma unroll
            for (int r = 0; r < 4; ++r) {
                const float val = acc[mt][nt][r] + bvv;
                const long long o = (row0 + r) * (long long)ldo + col;
                if (OUTBF) ((u16*)outp)[o] = f2bf(val);
                else       ((float*)outp)[o] = val;
            }
        }
    }
}

// Generic wrapper: z-batched via linear strides on A/W/bias/out.
template<int NSEG, int OUTBF>
__global__ __launch_bounds__(256, 2)
void gemm_seg_kernel(Seg s0, Seg s1, Seg s2, Seg s3,
                     const float* bias0, long long b0z,
                     const float* bias1, long long b1z,
                     void* outp, long long outz, int ldo)
{
    const int z = blockIdx.z;
    const Seg segsIn[4] = {s0, s1, s2, s3};
    SegR segs[NSEG];
#pragma unroll
    for (int i = 0; i < NSEG; ++i) {
        segs[i].A   = segsIn[i].A + (long long)z * segsIn[i].Az;
        segs[i].lda = segsIn[i].lda;
        segs[i].W   = segsIn[i].W + (long long)z * segsIn[i].Wz;
        segs[i].ldw = segsIn[i].ldw;
    }
    gemm_core<NSEG, OUTBF>(segs,
        bias0 + (long long)z * b0z,
        bias1 ? bias1 + (long long)z * b1z : nullptr,
        OUTBF ? (void*)((u16*)outp + (long long)z * outz)
              : (void*)((float*)outp + (long long)z * outz),
        ldo);
}

// q/k/v wrapper: z in [0,7): 0-2 = k[s], 3-5 = v[s], 6 = q.
__global__ __launch_bounds__(256, 2)
void qkv_gemm_kernel(const u16* __restrict__ hnew, const u16* __restrict__ ssm,
                     const u16* __restrict__ inpj, const float* __restrict__ ipb,
                     u16* __restrict__ kout, u16* __restrict__ vout,
                     u16* __restrict__ qout)
{
    const int z = blockIdx.z;
    const long long BD = (long long)Bq * Dq;
    SegR seg[1];
    const float* bias;
    u16* out;
    if (z < 3) {
        seg[0].A = hnew + z * BD;        seg[0].W = inpj + Dq * Dq;
        bias = ipb + Dq;                 out = kout + z * BD;
    } else if (z < 6) {
        seg[0].A = hnew + (z - 3) * BD;  seg[0].W = inpj + 2 * Dq * Dq;
        bias = ipb + 2 * Dq;             out = vout + (z - 3) * BD;
    } else {
        seg[0].A = ssm;                  seg[0].W = inpj;
        bias = ipb;                      out = qout;
    }
    seg[0].lda = Dq; seg[0].ldw = Dq;
    gemm_core<1, 1>(seg, bias, nullptr, out, Dq);
}

// ---------------------------------------------------------------------------
// LayerNorm + exact GELU, in-place on bf16 xs (S,B,D). One wave per row.
// ---------------------------------------------------------------------------
__global__ __launch_bounds__(256) void ln_gelu_kernel(u16* __restrict__ xs,
                                                      const float* __restrict__ ln_g,
                                                      const float* __restrict__ ln_b)
{
    const int lane = threadIdx.x & 63;
    const int wvi  = threadIdx.x >> 6;
    const long long row = (long long)blockIdx.x * 4 + wvi;   // row in [0, S*B)
    const int s = (int)(row >> 14);                           // row / Bq
    u16* p = xs + row * Dq + lane * 8;
    u16x8 u = *(const u16x8*)p;
    float v[8];
    float sum = 0.f, sq = 0.f;
#pragma unroll
    for (int j = 0; j < 8; ++j) { v[j] = bf2f(u[j]); sum += v[j]; sq += v[j] * v[j]; }
#pragma unroll
    for (int m = 32; m >= 1; m >>= 1) { sum += __shfl_xor(sum, m, 64); sq += __shfl_xor(sq, m, 64); }
    const float mu   = sum * (1.f / 512.f);
    const float var  = sq * (1.f / 512.f) - mu * mu;
    const float rstd = rsqrtf(var + 1e-5f);
    const float* g = ln_g + (size_t)s * Dq + lane * 8;
    const float* b = ln_b + (size_t)s * Dq + lane * 8;
    u16x8 o;
#pragma unroll
    for (int j = 0; j < 8; ++j) {
        float y  = (v[j] - mu) * rstd * g[j] + b[j];
        float ge = 0.5f * y * (1.f + erff(y * 0.70710678118654752f));   // exact GELU
        o[j] = f2bf(ge);
    }
    *(u16x8*)p = o;
}

// ---------------------------------------------------------------------------
// LSTM pointwise, all S in one launch: gates_all(bf16, S x B x 4D) + c_prev
//   -> h_new/c_new (fp32, into d_out) + h_new bf16 for downstream GEMMs.
// ---------------------------------------------------------------------------
__global__ __launch_bounds__(256) void lstm_kernel(const u16* __restrict__ gates_all,
                                                   const float* __restrict__ cprev,
                                                   const float* __restrict__ decays,
                                                   float* __restrict__ hout,
                                                   float* __restrict__ cout,
                                                   u16* __restrict__ hbf)
{
    const long long i = ((long long)blockIdx.x * 256 + threadIdx.x) * 4;  // over S*B*D
    const int s = (int)(i >> 23);                 // BD = 2^23
    const long long off = i & ((1LL << 23) - 1);
    const long long bi = off >> 9;
    const int d = (int)(off & 511);
    const u16* g = gates_all + ((long long)s << 25) + bi * 2048 + d;  // s*B*4D
    u16x4v ig = *(const u16x4v*)(g);
    u16x4v fg = *(const u16x4v*)(g + 512);
    u16x4v gg = *(const u16x4v*)(g + 1024);
    u16x4v og = *(const u16x4v*)(g + 1536);
    float4 cp4 = *(const float4*)(cprev + i);
    float cpa[4] = {cp4.x, cp4.y, cp4.z, cp4.w};
    const float dec = decays[s];
    float hv[4], cv[4]; u16x4v hb;
#pragma unroll
    for (int j = 0; j < 4; ++j) {
        float igf = 1.f / (1.f + expf(-bf2f(ig[j])));
        float fgf = 1.f / (1.f + expf(-bf2f(fg[j])));
        float ggf = tanhf(bf2f(gg[j]));
        float ogf = 1.f / (1.f + expf(-bf2f(og[j])));
        float cl  = fgf * cpa[j] + igf * ggf;
        float hn  = ogf * tanhf(cl);
        hv[j] = hn;
        cv[j] = dec * cpa[j] + (1.f - dec) * cl;
        hb[j] = f2bf(hn);
    }
    *(float4*)(hout + i) = make_float4(hv[0], hv[1], hv[2], hv[3]);
    *(float4*)(cout + i) = make_float4(cv[0], cv[1], cv[2], cv[3]);
    *(u16x4v*)(hbf + i)  = hb;
}

// ---------------------------------------------------------------------------
// Attention over S=3. One wave per (b,h); lane = head-dim element.
// ---------------------------------------------------------------------------
__global__ __launch_bounds__(256) void attn_kernel(const u16* __restrict__ q,
                                                   const u16* __restrict__ k,
                                                   const u16* __restrict__ v,
                                                   u16* __restrict__ fused)
{
    const int lane = threadIdx.x & 63;
    const int wvi  = threadIdx.x >> 6;
    const long long idx = (long long)blockIdx.x * 4 + wvi;   // b*H + h
    const long long off = idx * 64 + lane;                   // = b*512 + h*64 + lane
    const float qv = bf2f(q[off]);
    float sc[3];
#pragma unroll
    for (int s = 0; s < 3; ++s) {
        float p = qv * bf2f(k[(long long)s * Bq * Dq + off]);
#pragma unroll
        for (int m = 32; m >= 1; m >>= 1) p += __shfl_xor(p, m, 64);
        sc[s] = p * 0.125f;   // 1/sqrt(64)
    }
    const float mx = fmaxf(sc[0], fmaxf(sc[1], sc[2]));
    const float e0 = expf(sc[0] - mx), e1 = expf(sc[1] - mx), e2 = expf(sc[2] - mx);
    const float inv = 1.f / (e0 + e1 + e2);
    const float f = (e0 * bf2f(v[off]) +
                     e1 * bf2f(v[(long long)Bq * Dq + off]) +
                     e2 * bf2f(v[2LL * Bq * Dq + off])) * inv;
    fused[off] = f2bf(f);
}

// ---------------------------------------------------------------------------
// Host launcher
// ---------------------------------------------------------------------------
extern "C" void kernel_launch(void* const* d_in, const int* in_sizes, int n_in,
                              void* d_out, int out_size, void* d_ws, size_t ws_size,
                              hipStream_t stream)
{
    (void)in_sizes; (void)n_in; (void)out_size; (void)ws_size;

    const float* x         = (const float*)d_in[0];
    const float* h_prev    = (const float*)d_in[1];
    const float* c_prev    = (const float*)d_in[2];
    const float* ssm       = (const float*)d_in[3];
    const float* Wt        = (const float*)d_in[4];
    const float* bt        = (const float*)d_in[5];
    const float* ln_g      = (const float*)d_in[6];
    const float* ln_b      = (const float*)d_in[7];
    const float* W_ih      = (const float*)d_in[8];
    const float* W_hh      = (const float*)d_in[9];
    const float* b_ih      = (const float*)d_in[10];
    const float* b_hh      = (const float*)d_in[11];
    const float* decays    = (const float*)d_in[12];
    const float* in_proj_w = (const float*)d_in[13];
    const float* in_proj_b = (const float*)d_in[14];
    const float* out_proj_w= (const float*)d_in[15];
    const float* out_proj_b= (const float*)d_in[16];
    const float* mix_w     = (const float*)d_in[17];
    const float* mix_b     = (const float*)d_in[18];
    float* out = (float*)d_out;

    const long long BD = (long long)Bq * Dq;

    // ---- workspace layout (bf16 elements), ~405 MB peak with aliasing ----
    u16* base = (u16*)d_ws;
    size_t off = 0;
    auto walloc = [&](size_t n) { u16* p = base + off; off += (n + 4095) & ~(size_t)4095; return p; };
    u16* wt_bf    = walloc((size_t)Sq * Dq * Dq);
    u16* wih_bf   = walloc((size_t)Sq * 4 * Dq * Dq);
    u16* whh_bf   = walloc((size_t)Sq * 4 * Dq * Dq);
    u16* inpj_bf  = walloc((size_t)3 * Dq * Dq);
    u16* outpj_bf = walloc((size_t)Dq * Dq);
    u16* mix_bf   = walloc((size_t)Dq * Sq * Dq);
    u16* x_bf     = walloc((size_t)Bq * Dq);
    u16* ssm_bf   = walloc((size_t)Bq * Dq);
    u16* hprev_bf = walloc((size_t)Sq * Bq * Dq);
    u16* xs_bf    = walloc((size_t)Sq * Bq * Dq);
    u16* gates_bf = walloc((size_t)Sq * Bq * 4 * Dq);     // all S at once
    u16* hnew_bf  = walloc((size_t)Sq * Bq * Dq);
    u16* k_bf  = xs_bf;                     // xs dead after gates GEMM
    u16* v_bf  = hprev_bf;                  // h_prev dead after gates GEMM
    u16* q_bf  = gates_bf;                  // gates dead after LSTM
    u16* fu_bf = gates_bf + BD;

    // ---- one fused convert launch ----
    {
        CvtArgs a;
        const float* srcs[9] = {x, ssm, h_prev, Wt, W_ih, W_hh, in_proj_w, out_proj_w, mix_w};
        u16* dsts[9] = {x_bf, ssm_bf, hprev_bf, wt_bf, wih_bf, whh_bf, inpj_bf, outpj_bf, mix_bf};
        const long long ns[9] = {BD, BD, Sq * BD,
                                 (long long)Sq * Dq * Dq, (long long)Sq * 4 * Dq * Dq,
                                 (long long)Sq * 4 * Dq * Dq, (long long)3 * Dq * Dq,
                                 (long long)Dq * Dq, (long long)Dq * Sq * Dq};
        long long acc = 0;
        for (int i = 0; i < 9; ++i) { a.src[i] = srcs[i]; a.dst[i] = dsts[i]; acc += ns[i]; a.bound[i] = acc; }
        cvt_all_kernel<<<dim3((unsigned)((acc / 4 + 255) / 256)), 256, 0, stream>>>(a, acc);
    }

    Seg zs{nullptr, 0, 0, nullptr, 0, 0};

    // xs[s] = x @ Wt[s]^T + bt[s]     (z over S)
    {
        Seg a{x_bf, 0, Dq, wt_bf, (long long)Dq * Dq, Dq};
        gemm_seg_kernel<1, 1><<<dim3(Dq / 128, Bq / 128, Sq), 256, 0, stream>>>(
            a, zs, zs, zs, bt, Dq, nullptr, 0, xs_bf, BD, Dq);
    }
    ln_gelu_kernel<<<dim3(Sq * Bq / 4), 256, 0, stream>>>(xs_bf, ln_g, ln_b);

    // gates[s] = xs[s]@W_ih[s]^T + h_prev[s]@W_hh[s]^T + b_ih[s] + b_hh[s]  (z over S)
    {
        Seg a{xs_bf, BD, Dq, wih_bf, (long long)4 * Dq * Dq, Dq};
        Seg b{hprev_bf, BD, Dq, whh_bf, (long long)4 * Dq * Dq, Dq};
        gemm_seg_kernel<2, 1><<<dim3(4 * Dq / 128, Bq / 128, Sq), 256, 0, stream>>>(
            a, b, zs, zs, b_ih, 4 * Dq, b_hh, 4 * Dq, gates_bf, 4 * BD, 4 * Dq);
    }
    // LSTM pointwise, all S
    lstm_kernel<<<dim3(Sq * Bq * Dq / 1024), 256, 0, stream>>>(
        gates_bf, c_prev, decays,
        out + BD,                 // h_new slot
        out + 4 * BD,             // c_new slot
        hnew_bf);

    // q/k/v in one launch (z=7)
    qkv_gemm_kernel<<<dim3(Dq / 128, Bq / 128, 7), 256, 0, stream>>>(
        hnew_bf, ssm_bf, inpj_bf, in_proj_b, k_bf, v_bf, q_bf);

    attn_kernel<<<dim3(Bq * Hq / 4), 256, 0, stream>>>(q_bf, k_bf, v_bf, fu_bf);

    // out = sum_s h_new[s] @ mix_w[:, s*D:(s+1)*D]^T + fused @ out_proj^T
    //       + mix_b + out_proj_b          (4 K-segments; multi-transpose folded)
    {
        Seg a0{hnew_bf, 0, Dq, mix_bf, 0, Sq * Dq};
        Seg a1{hnew_bf + BD, 0, Dq, mix_bf + Dq, 0, Sq * Dq};
        Seg a2{hnew_bf + 2 * BD, 0, Dq, mix_bf + 2 * Dq, 0, Sq * Dq};
        Seg a3{fu_bf, 0, Dq, outpj_bf, 0, Dq};
        gemm_seg_kernel<4, 0><<<dim3(Dq / 128, Bq / 128, 1), 256, 0, stream>>>(
            a0, a1, a2, a3, mix_b, 0, out_proj_b, 0, out, 0, Dq);
    }
}